// Round 17
// baseline (196.850 us; speedup 1.0000x reference)
//
#include <hip/hip_runtime.h>

#define B_ 256
#define L_ 512
#define D_ 768
#define C_ 10331
#define CPT 10336         // padded C for WT layout
#define K_ 2304           // 3*D
#define GBK 64
#define NKIT (K_ / GBK)   // 36
#define NT 32             // out cols per block
#define NBLK 323          // ceil(C_/NT)

using v8bf = __attribute__((ext_vector_type(8))) __bf16;
using v4f  = __attribute__((ext_vector_type(4))) float;

__device__ __forceinline__ unsigned short f2bf(float f) {
    unsigned int u = __float_as_uint(f);
    unsigned int r = (u + 0x7FFFu + ((u >> 16) & 1u)) >> 16;   // RNE
    return (unsigned short)r;
}

__device__ __forceinline__ void fma4(float4& a, float w, const float4& v) {
    a.x = fmaf(w, v.x, a.x); a.y = fmaf(w, v.y, a.y);
    a.z = fmaf(w, v.z, a.z); a.w = fmaf(w, v.w, a.w);
}

// ---------------------------------------------------------------------------
// Kernel 1: count-based gather + masked means -> feats (B, 3D) bf16.
// (unchanged; ~13 us)
// ---------------------------------------------------------------------------
__global__ __launch_bounds__(512) void feats_gather(
    const float* __restrict__ seq,        // (B, L, D)
    const int*   __restrict__ head_index, // (B, L)
    const int*   __restrict__ start,
    const int*   __restrict__ end,
    unsigned short* __restrict__ feats)   // (B, 3D) bf16
{
    const int b    = blockIdx.x;
    const int t    = threadIdx.x;
    const int lane = t & 63;
    const int wave = t >> 6;              // 0..7

    __shared__ int idx_sh[L_];
    __shared__ int cnt_sh[3][L_];
    __shared__ int list_sh[L_];
    __shared__ int nz_sh, nlist_sh;
    __shared__ float4 red_sh[8][3][192];  // 72 KB

    if (t == 0) nz_sh = 0;
    cnt_sh[0][t] = 0; cnt_sh[1][t] = 0; cnt_sh[2][t] = 0;
    const int v = head_index[b * L_ + t];
    idx_sh[t] = v;
    unsigned long long ball = __ballot(v != 0);
    __syncthreads();
    if (lane == 0) atomicAdd(&nz_sh, (int)__popcll(ball));
    __syncthreads();

    const int right_len = nz_sh;
    const int s = start[b];
    const int e = end[b];

    if (t < right_len) {
        int r = (t < s) ? 0 : ((t < e) ? 1 : 2);
        atomicAdd(&cnt_sh[r][v], 1);
    }
    __syncthreads();

    if (wave == 0) {
        int maskbits = 0, csum = 0;
        const int j0 = lane * 8;
        #pragma unroll
        for (int k = 0; k < 8; ++k) {
            int j = j0 + k;
            if (cnt_sh[0][j] | cnt_sh[1][j] | cnt_sh[2][j]) { maskbits |= (1 << k); ++csum; }
        }
        int incl = csum;
        #pragma unroll
        for (int off = 1; off < 64; off <<= 1) {
            int x = __shfl_up(incl, off, 64);
            if (lane >= off) incl += x;
        }
        int pos = incl - csum;
        #pragma unroll
        for (int k = 0; k < 8; ++k)
            if (maskbits & (1 << k)) list_sh[pos++] = j0 + k;
        if (lane == 63) nlist_sh = incl;
    }
    __syncthreads();

    const int nlist = nlist_sh;
    const int nl = s, nm = e - s, nr = right_len - e;
    const float rs0 = (nl > 0) ? 1.0f / (float)nl : 0.0f;
    const float rs1 = (nm > 0) ? 1.0f / (float)nm : 0.0f;
    const float rs2 = (nr > 0) ? 1.0f / (float)nr : 0.0f;

    const float4* seqb4 = reinterpret_cast<const float4*>(seq + (size_t)b * L_ * D_);

    float4 acc[3][3];
    #pragma unroll
    for (int r = 0; r < 3; ++r)
        #pragma unroll
        for (int jj = 0; jj < 3; ++jj)
            acc[r][jj] = make_float4(0.f, 0.f, 0.f, 0.f);

    int i = wave;
    for (; i + 8 < nlist; i += 16) {
        const int ja = list_sh[i], jb = list_sh[i + 8];
        const float4* rowa = seqb4 + (size_t)ja * 192;
        const float4* rowb = seqb4 + (size_t)jb * 192;
        float wa0 = (float)cnt_sh[0][ja] * rs0;
        float wa1 = (float)cnt_sh[1][ja] * rs1;
        float wa2 = (float)cnt_sh[2][ja] * rs2;
        float wb0 = (float)cnt_sh[0][jb] * rs0;
        float wb1 = (float)cnt_sh[1][jb] * rs1;
        float wb2 = (float)cnt_sh[2][jb] * rs2;
        #pragma unroll
        for (int jj = 0; jj < 3; ++jj) {
            float4 va = rowa[jj * 64 + lane];
            float4 vb = rowb[jj * 64 + lane];
            fma4(acc[0][jj], wa0, va); fma4(acc[1][jj], wa1, va); fma4(acc[2][jj], wa2, va);
            fma4(acc[0][jj], wb0, vb); fma4(acc[1][jj], wb1, vb); fma4(acc[2][jj], wb2, vb);
        }
    }
    if (i < nlist) {
        const int ja = list_sh[i];
        const float4* rowa = seqb4 + (size_t)ja * 192;
        float wa0 = (float)cnt_sh[0][ja] * rs0;
        float wa1 = (float)cnt_sh[1][ja] * rs1;
        float wa2 = (float)cnt_sh[2][ja] * rs2;
        #pragma unroll
        for (int jj = 0; jj < 3; ++jj) {
            float4 va = rowa[jj * 64 + lane];
            fma4(acc[0][jj], wa0, va); fma4(acc[1][jj], wa1, va); fma4(acc[2][jj], wa2, va);
        }
    }

    #pragma unroll
    for (int r = 0; r < 3; ++r)
        #pragma unroll
        for (int jj = 0; jj < 3; ++jj)
            red_sh[wave][r][jj * 64 + lane] = acc[r][jj];
    __syncthreads();

    for (int w = t; w < 576; w += 512) {
        int reg = w / 192, pos = w - reg * 192;
        float4 sum = red_sh[0][reg][pos];
        #pragma unroll
        for (int wv = 1; wv < 8; ++wv) {
            float4 x = red_sh[wv][reg][pos];
            sum.x += x.x; sum.y += x.y; sum.z += x.z; sum.w += x.w;
        }
        ushort4 u;
        u.x = f2bf(sum.x); u.y = f2bf(sum.y); u.z = f2bf(sum.z); u.w = f2bf(sum.w);
        *(ushort4*)(&feats[(size_t)b * K_ + reg * D_ + pos * 4]) = u;
    }
}

// ---------------------------------------------------------------------------
// Kernel 2: W (C,K) fp32 -> WT[kt][c][64] bf16  (k-tiled transpose+convert)
// Wave-unit = (c-group of 16, kt-batch of 4). Lane (cg 16 x kt 4):
// reads 256B contiguous per lane (4 lanes cover 1KB of one row);
// writes: per kt, 16 c x 128B = 2KB contiguous burst.
// ---------------------------------------------------------------------------
#define NCG 646           // ceil(C_/16)
#define CONV_WU (NCG * 9) // wave-units
__global__ __launch_bounds__(256) void wconv(
    const float* __restrict__ W,
    unsigned short* __restrict__ WT)
{
    const int wid0 = blockIdx.x * 4 + (threadIdx.x >> 6);
    const int lane = threadIdx.x & 63;
    if (wid0 >= CONV_WU) return;
    const int cg  = wid0 / 9;
    const int ktb = wid0 - cg * 9;
    const int c   = cg * 16 + (lane >> 2);
    const int kt  = ktb * 4 + (lane & 3);
    if (c >= C_) return;

    const float4* src = (const float4*)(W + (size_t)c * K_ + kt * 64);
    unsigned short* dst = WT + ((size_t)kt * CPT + c) * 64;

    #pragma unroll
    for (int j = 0; j < 8; ++j) {
        float4 a = src[j * 2 + 0];
        float4 b = src[j * 2 + 1];
        ushort4 u0, u1;
        u0.x = f2bf(a.x); u0.y = f2bf(a.y); u0.z = f2bf(a.z); u0.w = f2bf(a.w);
        u1.x = f2bf(b.x); u1.y = f2bf(b.y); u1.z = f2bf(b.z); u1.w = f2bf(b.w);
        *(ushort4*)(dst + j * 8 + 0) = u0;
        *(ushort4*)(dst + j * 8 + 4) = u1;
    }
}

// ---------------------------------------------------------------------------
// Kernel 3: out = feats(bf16) @ WT^T + bias — NO LDS, NO BARRIERS.
// Block = 32 cols x 256 batch, 512 thr, 8 free-running waves (wave = 32
// batch rows, m=2, n=2, kk=2 -> 8 MFMA/phase). B-frags: 16B/lane fully
// coalesced from WT (L2/HBM sequential slabs). A-frags from L2 (feats is
// 1.18MB, L2-resident). Compiler software-pipelines freely across phases.
// ---------------------------------------------------------------------------
__global__ __launch_bounds__(512, 4) void mfma_gemm(
    const unsigned short* __restrict__ A,   // (B_, K_) bf16
    const unsigned short* __restrict__ WT,  // [36][CPT][64] bf16
    const float* __restrict__ bias,
    float*       __restrict__ out)          // (B_, C_) f32
{
    const int t    = threadIdx.x;
    const int lane = t & 63;
    const int wave = t >> 6;          // 0..7
    const int frow = lane & 15;
    const int q    = lane >> 4;       // 0..3
    const int col0 = blockIdx.x * NT;

    const unsigned short* a_base  = A + (size_t)(wave * 32 + frow) * K_ + q * 8;
    const unsigned short* wt_base = WT + ((size_t)col0 + frow) * 64 + q * 8;

    v4f acc[2][2] = {};

    #pragma unroll 4
    for (int it = 0; it < NKIT; ++it) {
        v8bf af[2][2], bfr[2][2];
        #pragma unroll
        for (int n = 0; n < 2; ++n)
            #pragma unroll
            for (int kk = 0; kk < 2; ++kk)
                bfr[n][kk] = *(const v8bf*)(wt_base + (size_t)it * (CPT * 64) + n * (16 * 64) + kk * 32);
        #pragma unroll
        for (int m = 0; m < 2; ++m)
            #pragma unroll
            for (int kk = 0; kk < 2; ++kk)
                af[m][kk] = *(const v8bf*)(a_base + (size_t)m * (16 * K_) + it * 64 + kk * 32);
        #pragma unroll
        for (int kk = 0; kk < 2; ++kk)
            #pragma unroll
            for (int m = 0; m < 2; ++m)
                #pragma unroll
                for (int n = 0; n < 2; ++n)
                    acc[m][n] = __builtin_amdgcn_mfma_f32_16x16x32_bf16(af[m][kk], bfr[n][kk], acc[m][n], 0, 0, 0);
    }

    // ---- epilogue: direct out + bias ----
    const int crow = wave * 32 + q * 4;
    const int ccol = col0 + frow;
    #pragma unroll
    for (int n = 0; n < 2; ++n) {
        int col = ccol + n * 16;
        if (col < C_) {
            float bv = bias[col];
            #pragma unroll
            for (int m = 0; m < 2; ++m)
                #pragma unroll
                for (int r = 0; r < 4; ++r)
                    out[(size_t)(crow + m * 16 + r) * C_ + col] = acc[m][n][r] + bv;
        }
    }
}

// ---------------------------------------------------------------------------
extern "C" void kernel_launch(void* const* d_in, const int* in_sizes, int n_in,
                              void* d_out, int out_size, void* d_ws, size_t ws_size,
                              hipStream_t stream) {
    const float* seq        = (const float*)d_in[0];
    const int*   head_index = (const int*)  d_in[1];
    const int*   start      = (const int*)  d_in[2];
    const int*   end        = (const int*)  d_in[3];
    const float* W          = (const float*)d_in[4];
    const float* bias       = (const float*)d_in[5];
    float*       out        = (float*)d_out;

    unsigned short* feats = (unsigned short*)d_ws;                  // 1.18 MB
    unsigned short* WT    = (unsigned short*)((char*)d_ws + ((size_t)2 << 20)); // 47.6 MB

    feats_gather<<<dim3(B_), dim3(512), 0, stream>>>(seq, head_index, start, end, feats);
    wconv<<<dim3((CONV_WU + 3) / 4), dim3(256), 0, stream>>>(W, WT);
    mfma_gemm<<<dim3(NBLK), dim3(512), 0, stream>>>(feats, WT, bias, out);
}

// Round 18
// 87.172 us; speedup vs baseline: 2.2582x; 2.2582x over previous
//
#include <hip/hip_runtime.h>

#define B_ 256
#define L_ 512
#define D_ 768
#define C_ 10331
#define K_ 2304           // 3*D
#define CPAD 10368        // 162*64
#define KSPLIT 4
#define KSL (K_ / KSPLIT) // 576
#define GBK 64
#define NKIT (KSL / GBK)  // 9

using v8bf = __attribute__((ext_vector_type(8))) __bf16;
using v4f  = __attribute__((ext_vector_type(4))) float;

__device__ __forceinline__ unsigned short f2bf(float f) {
    unsigned int u = __float_as_uint(f);
    unsigned int r = (u + 0x7FFFu + ((u >> 16) & 1u)) >> 16;   // RNE
    return (unsigned short)r;
}

__device__ __forceinline__ void fma4(float4& a, float w, const float4& v) {
    a.x = fmaf(w, v.x, a.x); a.y = fmaf(w, v.y, a.y);
    a.z = fmaf(w, v.z, a.z); a.w = fmaf(w, v.w, a.w);
}

// ---------------------------------------------------------------------------
// Kernel 1: count-based gather + masked means -> feats (B, 3D) bf16.
// (unchanged; ~13 us)
// ---------------------------------------------------------------------------
__global__ __launch_bounds__(512) void feats_gather(
    const float* __restrict__ seq,        // (B, L, D)
    const int*   __restrict__ head_index, // (B, L)
    const int*   __restrict__ start,
    const int*   __restrict__ end,
    unsigned short* __restrict__ feats)   // (B, 3D) bf16
{
    const int b    = blockIdx.x;
    const int t    = threadIdx.x;
    const int lane = t & 63;
    const int wave = t >> 6;              // 0..7

    __shared__ int idx_sh[L_];
    __shared__ int cnt_sh[3][L_];
    __shared__ int list_sh[L_];
    __shared__ int nz_sh, nlist_sh;
    __shared__ float4 red_sh[8][3][192];  // 72 KB

    if (t == 0) nz_sh = 0;
    cnt_sh[0][t] = 0; cnt_sh[1][t] = 0; cnt_sh[2][t] = 0;
    const int v = head_index[b * L_ + t];
    idx_sh[t] = v;
    unsigned long long ball = __ballot(v != 0);
    __syncthreads();
    if (lane == 0) atomicAdd(&nz_sh, (int)__popcll(ball));
    __syncthreads();

    const int right_len = nz_sh;
    const int s = start[b];
    const int e = end[b];

    if (t < right_len) {
        int r = (t < s) ? 0 : ((t < e) ? 1 : 2);
        atomicAdd(&cnt_sh[r][v], 1);
    }
    __syncthreads();

    if (wave == 0) {
        int maskbits = 0, csum = 0;
        const int j0 = lane * 8;
        #pragma unroll
        for (int k = 0; k < 8; ++k) {
            int j = j0 + k;
            if (cnt_sh[0][j] | cnt_sh[1][j] | cnt_sh[2][j]) { maskbits |= (1 << k); ++csum; }
        }
        int incl = csum;
        #pragma unroll
        for (int off = 1; off < 64; off <<= 1) {
            int x = __shfl_up(incl, off, 64);
            if (lane >= off) incl += x;
        }
        int pos = incl - csum;
        #pragma unroll
        for (int k = 0; k < 8; ++k)
            if (maskbits & (1 << k)) list_sh[pos++] = j0 + k;
        if (lane == 63) nlist_sh = incl;
    }
    __syncthreads();

    const int nlist = nlist_sh;
    const int nl = s, nm = e - s, nr = right_len - e;
    const float rs0 = (nl > 0) ? 1.0f / (float)nl : 0.0f;
    const float rs1 = (nm > 0) ? 1.0f / (float)nm : 0.0f;
    const float rs2 = (nr > 0) ? 1.0f / (float)nr : 0.0f;

    const float4* seqb4 = reinterpret_cast<const float4*>(seq + (size_t)b * L_ * D_);

    float4 acc[3][3];
    #pragma unroll
    for (int r = 0; r < 3; ++r)
        #pragma unroll
        for (int jj = 0; jj < 3; ++jj)
            acc[r][jj] = make_float4(0.f, 0.f, 0.f, 0.f);

    int i = wave;
    for (; i + 8 < nlist; i += 16) {
        const int ja = list_sh[i], jb = list_sh[i + 8];
        const float4* rowa = seqb4 + (size_t)ja * 192;
        const float4* rowb = seqb4 + (size_t)jb * 192;
        float wa0 = (float)cnt_sh[0][ja] * rs0;
        float wa1 = (float)cnt_sh[1][ja] * rs1;
        float wa2 = (float)cnt_sh[2][ja] * rs2;
        float wb0 = (float)cnt_sh[0][jb] * rs0;
        float wb1 = (float)cnt_sh[1][jb] * rs1;
        float wb2 = (float)cnt_sh[2][jb] * rs2;
        #pragma unroll
        for (int jj = 0; jj < 3; ++jj) {
            float4 va = rowa[jj * 64 + lane];
            float4 vb = rowb[jj * 64 + lane];
            fma4(acc[0][jj], wa0, va); fma4(acc[1][jj], wa1, va); fma4(acc[2][jj], wa2, va);
            fma4(acc[0][jj], wb0, vb); fma4(acc[1][jj], wb1, vb); fma4(acc[2][jj], wb2, vb);
        }
    }
    if (i < nlist) {
        const int ja = list_sh[i];
        const float4* rowa = seqb4 + (size_t)ja * 192;
        float wa0 = (float)cnt_sh[0][ja] * rs0;
        float wa1 = (float)cnt_sh[1][ja] * rs1;
        float wa2 = (float)cnt_sh[2][ja] * rs2;
        #pragma unroll
        for (int jj = 0; jj < 3; ++jj) {
            float4 va = rowa[jj * 64 + lane];
            fma4(acc[0][jj], wa0, va); fma4(acc[1][jj], wa1, va); fma4(acc[2][jj], wa2, va);
        }
    }

    #pragma unroll
    for (int r = 0; r < 3; ++r)
        #pragma unroll
        for (int jj = 0; jj < 3; ++jj)
            red_sh[wave][r][jj * 64 + lane] = acc[r][jj];
    __syncthreads();

    for (int w = t; w < 576; w += 512) {
        int reg = w / 192, pos = w - reg * 192;
        float4 sum = red_sh[0][reg][pos];
        #pragma unroll
        for (int wv = 1; wv < 8; ++wv) {
            float4 x = red_sh[wv][reg][pos];
            sum.x += x.x; sum.y += x.y; sum.z += x.z; sum.w += x.w;
        }
        ushort4 u;
        u.x = f2bf(sum.x); u.y = f2bf(sum.y); u.z = f2bf(sum.z); u.w = f2bf(sum.w);
        *(ushort4*)(&feats[(size_t)b * K_ + reg * D_ + pos * 4]) = u;
    }
}

// ---------------------------------------------------------------------------
// Kernel 2: part[ks] = feats(bf16) @ W[:,kslice]^T — r10 structure at 512thr.
// Tile 256x64, 8 waves (wave = 32 rows x 64 cols; m2,n4,kk2 = 16 MFMA/phase).
// A-frag reg double-buffer issued BEFORE W loads each phase (keeps W stream
// in flight under the af vmcnt-wait). W: 3-slot reg prefetch -> bf16 LDS
// double buffer, XOR-swizzled (conflict-free read & write). grid (162,4) =
// 648 blocks ~ 2.5/CU; launch_bounds(512,4) => VGPR<=128, 2 blocks/CU
// resident for cross-block phase overlap (m114).
// ---------------------------------------------------------------------------
__global__ __launch_bounds__(512, 4) void mfma_gemm(
    const unsigned short* __restrict__ A,  // (B_, K_) bf16
    const float* __restrict__ W,           // (C_, K_) fp32
    float*       __restrict__ part)        // (KSPLIT, B_, CPAD) f32
{
    __shared__ char Bs0[64 * 128];   // 8 KB (64 rows x 64 bf16)
    __shared__ char Bs1[64 * 128];   // 8 KB

    const int t    = threadIdx.x;
    const int lane = t & 63;
    const int wave = t >> 6;          // 0..7
    const int frow = lane & 15;
    const int q    = lane >> 4;       // 0..3
    const int col0 = blockIdx.x * 64;
    const int kbase = blockIdx.y * KSL;

    const unsigned short* a_base = A + (size_t)(wave * 32 + frow) * K_ + kbase + q * 8;

    // W staging coords: thread t covers (row sr = t>>3, 32B chunk sc = t&7)
    const int sr = t >> 3;            // 0..63
    const int sc = t & 7;
    int gr = col0 + sr; if (gr > C_ - 1) gr = C_ - 1;
    const float* wrow = W + (size_t)gr * K_ + kbase + sc * 8;
    const int wb = sr * 128 + ((sc * 16) ^ ((sr & 7) << 4));  // swizzled 16B dest

    v4f  acc[2][4] = {};
    v8bf afA[2][2], afB[2][2];
    float4 rb0[2], rb1[2], rb2[2];

#define LOAD_B(DST, IT) { \
        DST[0] = *(const float4*)(wrow + (IT) * GBK); \
        DST[1] = *(const float4*)(wrow + (IT) * GBK + 4); }

#define WRITE_B(BUF, SRC) { \
        union { ushort uu[8]; int4 i4; } pk_; \
        pk_.uu[0] = f2bf(SRC[0].x); pk_.uu[1] = f2bf(SRC[0].y); \
        pk_.uu[2] = f2bf(SRC[0].z); pk_.uu[3] = f2bf(SRC[0].w); \
        pk_.uu[4] = f2bf(SRC[1].x); pk_.uu[5] = f2bf(SRC[1].y); \
        pk_.uu[6] = f2bf(SRC[1].z); pk_.uu[7] = f2bf(SRC[1].w); \
        *(int4*)((BUF) + wb) = pk_.i4; }

#define LOAD_AF(DST, IT) { \
        _Pragma("unroll") \
        for (int m_ = 0; m_ < 2; ++m_) \
            _Pragma("unroll") \
            for (int kk_ = 0; kk_ < 2; ++kk_) \
                DST[m_][kk_] = *(const v8bf*)(a_base + (size_t)m_ * 16 * K_ + (IT) * GBK + kk_ * 32); }

#define COMPUTE(AF, BUF) { \
        v8bf bfr[4][2]; \
        _Pragma("unroll") \
        for (int n_ = 0; n_ < 4; ++n_) { \
            int row_ = n_ * 16 + frow; \
            int sw_  = (row_ & 7) << 4; \
            _Pragma("unroll") \
            for (int kk_ = 0; kk_ < 2; ++kk_) \
                bfr[n_][kk_] = *(const v8bf*)((BUF) + row_ * 128 + ((kk_ * 64 + q * 16) ^ sw_)); } \
        _Pragma("unroll") \
        for (int kk_ = 0; kk_ < 2; ++kk_) \
            _Pragma("unroll") \
            for (int m_ = 0; m_ < 2; ++m_) \
                _Pragma("unroll") \
                for (int n_ = 0; n_ < 4; ++n_) \
                    acc[m_][n_] = __builtin_amdgcn_mfma_f32_16x16x32_bf16(AF[m_][kk_], bfr[n_][kk_], acc[m_][n_], 0, 0, 0); }

    // prologue: A first (oldest), then 3 W slots
    LOAD_AF(afA, 0)
    LOAD_B(rb0, 0) LOAD_B(rb1, 1) LOAD_B(rb2, 2)

    #pragma unroll
    for (int it = 0; it < NKIT; ++it) {
        char* buf = (it & 1) ? Bs1 : Bs0;
        if      ((it % 3) == 0) { WRITE_B(buf, rb0) }
        else if ((it % 3) == 1) { WRITE_B(buf, rb1) }
        else                    { WRITE_B(buf, rb2) }
        __syncthreads();
        if ((it & 1) == 0) { if (it + 1 < NKIT) LOAD_AF(afB, it + 1) }
        else               { if (it + 1 < NKIT) LOAD_AF(afA, it + 1) }
        if (it + 3 < NKIT) {
            if      ((it % 3) == 0) { LOAD_B(rb0, it + 3) }
            else if ((it % 3) == 1) { LOAD_B(rb1, it + 3) }
            else                    { LOAD_B(rb2, it + 3) }
        }
        if ((it & 1) == 0) { COMPUTE(afA, buf) }
        else               { COMPUTE(afB, buf) }
    }

    // ---- epilogue: fp32 partial, padded C (unguarded) ----
    float* p = part + (size_t)blockIdx.y * B_ * CPAD;
    const int crow = wave * 32 + q * 4;
    const int ccol = col0 + frow;
    #pragma unroll
    for (int n = 0; n < 4; ++n) {
        int col = ccol + n * 16;
        #pragma unroll
        for (int m = 0; m < 2; ++m)
            #pragma unroll
            for (int r = 0; r < 4; ++r)
                p[(size_t)(crow + m * 16 + r) * CPAD + col] = acc[m][n][r];
    }
#undef LOAD_B
#undef WRITE_B
#undef LOAD_AF
#undef COMPUTE
}

// ---------------------------------------------------------------------------
// Kernel 3: out[b,c] = sum_s part[s][b][c] + bias[c]; grid B_*4 quarter-rows.
// ---------------------------------------------------------------------------
__global__ __launch_bounds__(256) void reduce_bias(
    const float* __restrict__ part,
    const float* __restrict__ bias,
    float*       __restrict__ out)
{
    const int row = blockIdx.x >> 2;
    const int qd  = blockIdx.x & 3;
    const int t = threadIdx.x;
    const int NQ  = CPAD / 4;        // 2592
    const int NQQ = NQ / 4;          // 648

    const float4* p0 = (const float4*)(part + (size_t)0 * B_ * CPAD + (size_t)row * CPAD);
    const float4* p1 = (const float4*)(part + (size_t)1 * B_ * CPAD + (size_t)row * CPAD);
    const float4* p2 = (const float4*)(part + (size_t)2 * B_ * CPAD + (size_t)row * CPAD);
    const float4* p3 = (const float4*)(part + (size_t)3 * B_ * CPAD + (size_t)row * CPAD);
    float* orow = out + (size_t)row * C_;

    const int c4lo = qd * NQQ, c4hi = c4lo + NQQ;
    for (int c4 = c4lo + t; c4 < c4hi; c4 += 256) {
        float4 a = p0[c4], b = p1[c4], c = p2[c4], d = p3[c4];
        float s0 = a.x + b.x + c.x + d.x;
        float s1 = a.y + b.y + c.y + d.y;
        float s2 = a.z + b.z + c.z + d.z;
        float s3 = a.w + b.w + c.w + d.w;
        int cc = c4 * 4;
        if (cc + 3 < C_) {
            float4 bv = ((const float4*)bias)[c4];
            orow[cc + 0] = s0 + bv.x;
            orow[cc + 1] = s1 + bv.y;
            orow[cc + 2] = s2 + bv.z;
            orow[cc + 3] = s3 + bv.w;
        } else {
            if (cc + 0 < C_) orow[cc + 0] = s0 + bias[cc + 0];
            if (cc + 1 < C_) orow[cc + 1] = s1 + bias[cc + 1];
            if (cc + 2 < C_) orow[cc + 2] = s2 + bias[cc + 2];
            if (cc + 3 < C_) orow[cc + 3] = s3 + bias[cc + 3];
        }
    }
}

// ---------------------------------------------------------------------------
extern "C" void kernel_launch(void* const* d_in, const int* in_sizes, int n_in,
                              void* d_out, int out_size, void* d_ws, size_t ws_size,
                              hipStream_t stream) {
    const float* seq        = (const float*)d_in[0];
    const int*   head_index = (const int*)  d_in[1];
    const int*   start      = (const int*)  d_in[2];
    const int*   end        = (const int*)  d_in[3];
    const float* W          = (const float*)d_in[4];
    const float* bias       = (const float*)d_in[5];
    float*       out        = (float*)d_out;

    unsigned short* feats = (unsigned short*)d_ws;                 // 1.18 MB
    float* part = (float*)((char*)d_ws + ((size_t)2 << 20));       // 42.5 MB

    feats_gather<<<dim3(B_), dim3(512), 0, stream>>>(seq, head_index, start, end, feats);

    dim3 grid(CPAD / 64, KSPLIT);   // (162, 4) = 648 blocks
    mfma_gemm<<<grid, dim3(512), 0, stream>>>(feats, W, part);

    reduce_bias<<<dim3(B_ * 4), dim3(256), 0, stream>>>(part, bias, out);
}